// Round 1
// baseline (274.676 us; speedup 1.0000x reference)
//
#include <hip/hip_runtime.h>

// Problem constants (fixed by reference)
constexpr int N_  = 10000;   // nodes
constexpr int E_  = 320000;  // edges
constexpr int F1  = 33;      // input features
constexpr int H   = 32;      // hidden
constexpr int G   = 64;      // graphs

// ---------------- CSR build ----------------

__global__ void hist_kernel(const int* __restrict__ ei, int* __restrict__ counts) {
    int e = blockIdx.x * blockDim.x + threadIdx.x;
    if (e >= E_) return;
    int d = ei[E_ + e];          // dst row
    atomicAdd(&counts[d], 1);
}

// single-block exclusive scan of counts[0..N_-1] -> indptr[0..N_], copy into cursor
__global__ void scan_kernel(const int* __restrict__ counts,
                            int* __restrict__ indptr, int* __restrict__ cursor) {
    const int T = 1024, C = 10;  // T*C = 10240 >= N_
    __shared__ int part[T];
    int t = threadIdx.x;
    int local[C];
    int s = 0;
    #pragma unroll
    for (int j = 0; j < C; ++j) {
        int i = t * C + j;
        int v = (i < N_) ? counts[i] : 0;
        local[j] = s;            // exclusive within thread-chunk
        s += v;
    }
    part[t] = s;
    __syncthreads();
    // Kogge-Stone inclusive scan over part[]
    for (int off = 1; off < T; off <<= 1) {
        int x = (t >= off) ? part[t - off] : 0;
        __syncthreads();
        part[t] += x;
        __syncthreads();
    }
    int excl = part[t] - s;      // exclusive prefix of this thread's chunk
    #pragma unroll
    for (int j = 0; j < C; ++j) {
        int i = t * C + j;
        if (i < N_) {
            int val = excl + local[j];
            indptr[i] = val;
            cursor[i] = val;
        }
    }
    if (t == T - 1) indptr[N_] = part[t];
}

__global__ void place_kernel(const int* __restrict__ ei, const float* __restrict__ ea,
                             int* __restrict__ cursor,
                             int* __restrict__ esrc, float* __restrict__ eav) {
    int e = blockIdx.x * blockDim.x + threadIdx.x;
    if (e >= E_) return;
    int s = ei[e];
    int d = ei[E_ + e];
    int pos = atomicAdd(&cursor[d], 1);
    esrc[pos] = s;
    eav[pos]  = ea[e];
}

// ---------------- Per-layer node precompute: U = X@A, V = X@B, R = X@root + bias --------

__global__ void precompute_kernel(const float* __restrict__ X, int Fin,
                                  const float* __restrict__ A,   // nn_w  [Fin*H]
                                  const float* __restrict__ B,   // nn_b  [Fin*H]
                                  const float* __restrict__ Rw,  // root  [Fin*H]
                                  const float* __restrict__ bias,// [H]
                                  float* __restrict__ U, float* __restrict__ V,
                                  float* __restrict__ R) {
    int gid = blockIdx.x * blockDim.x + threadIdx.x;
    int i = gid >> 5;
    int f = gid & 31;
    if (i >= N_) return;
    float u = 0.f, v = 0.f, r = bias[f];
    const float* xr = X + (size_t)i * Fin;
    for (int k = 0; k < Fin; ++k) {
        float x = xr[k];
        u = fmaf(x, A[k * H + f], u);
        v = fmaf(x, B[k * H + f], v);
        r = fmaf(x, Rw[k * H + f], r);
    }
    U[i * H + f] = u;
    V[i * H + f] = v;
    R[i * H + f] = r;
}

// ---------------- Conv aggregate: h[i] = relu(R[i] + sum_e a_e*U[src]+V[src]) ----------

__global__ void conv_agg_kernel(const int* __restrict__ indptr,
                                const int* __restrict__ esrc,
                                const float* __restrict__ eav,
                                const float* __restrict__ U, const float* __restrict__ V,
                                const float* __restrict__ R,
                                float* __restrict__ Hout) {
    int gid = blockIdx.x * blockDim.x + threadIdx.x;
    int node = gid >> 5;
    int f = gid & 31;
    if (node >= N_) return;
    float acc = R[node * H + f];
    int s = indptr[node];
    int e = indptr[node + 1];
    for (int j = s; j < e; ++j) {
        int src = esrc[j];
        float a = eav[j];
        acc += a * U[src * H + f] + V[src * H + f];
    }
    Hout[node * H + f] = (acc > 0.f) ? acc : 0.f;   // relu, force +0
}

// ---------------- Pooling: add / count / max per graph (batch is sorted) ----------------

__global__ void pool_kernel(const float* __restrict__ Hm, const int* __restrict__ batch,
                            float* __restrict__ add_p, float* __restrict__ cnt,
                            unsigned int* __restrict__ max_p) {
    // each thread: feature f, 8 consecutive nodes; run-length compress atomics
    int gid = blockIdx.x * blockDim.x + threadIdx.x;
    int f  = gid & 31;
    int i0 = (gid >> 5) * 8;
    if (i0 >= N_) return;
    int iend = min(i0 + 8, N_);
    int curb = batch[i0];
    float s = 0.f, mx = 0.f, c = 0.f;
    for (int i = i0; i < iend; ++i) {
        int b = batch[i];
        if (b != curb) {
            atomicAdd(&add_p[curb * H + f], s);
            atomicMax(&max_p[curb * H + f], __float_as_uint(mx));
            if (f == 0) atomicAdd(&cnt[curb], c);
            curb = b; s = 0.f; mx = 0.f; c = 0.f;
        }
        float h = Hm[i * H + f];
        s += h;
        mx = fmaxf(mx, h);
        c += 1.f;
    }
    atomicAdd(&add_p[curb * H + f], s);
    atomicMax(&max_p[curb * H + f], __float_as_uint(mx));
    if (f == 0) atomicAdd(&cnt[curb], c);
}

// ---------------- Readout MLP + log_softmax ----------------

__global__ void readout_kernel(const float* __restrict__ add_p, const float* __restrict__ cnt,
                               const unsigned int* __restrict__ max_p,
                               const float* __restrict__ w1, const float* __restrict__ b1,
                               const float* __restrict__ w2, const float* __restrict__ b2,
                               float* __restrict__ out) {
    int g = blockIdx.x;      // G blocks
    int f = threadIdx.x;     // 64 threads (use first 32)
    __shared__ float gv[3 * H];
    __shared__ float hid[H];
    if (f < H) {
        float a = add_p[g * H + f];
        float c = fmaxf(cnt[g], 1.0f);
        gv[f]         = a;
        gv[H + f]     = a / c;
        gv[2 * H + f] = __uint_as_float(max_p[g * H + f]);
    }
    __syncthreads();
    if (f < H) {
        float acc = b1[f];
        #pragma unroll 4
        for (int k = 0; k < 3 * H; ++k) acc = fmaf(gv[k], w1[k * H + f], acc);
        hid[f] = (acc > 0.f) ? acc : 0.f;
    }
    __syncthreads();
    if (f == 0) {
        float l0 = b2[0], l1 = b2[1];
        for (int k = 0; k < H; ++k) {
            l0 = fmaf(hid[k], w2[k * 2 + 0], l0);
            l1 = fmaf(hid[k], w2[k * 2 + 1], l1);
        }
        float m = fmaxf(l0, l1);
        float lse = m + logf(expf(l0 - m) + expf(l1 - m));
        out[g * 2 + 0] = l0 - lse;
        out[g * 2 + 1] = l1 - lse;
    }
}

// ---------------- launch ----------------

extern "C" void kernel_launch(void* const* d_in, const int* in_sizes, int n_in,
                              void* d_out, int out_size, void* d_ws, size_t ws_size,
                              hipStream_t stream) {
    const float* x      = (const float*)d_in[0];
    const int*   ei     = (const int*)  d_in[1];
    const float* ea     = (const float*)d_in[2];
    const int*   batch  = (const int*)  d_in[3];
    const float* nn_w1  = (const float*)d_in[4];
    const float* nn_b1  = (const float*)d_in[5];
    const float* root1  = (const float*)d_in[6];
    const float* bias1  = (const float*)d_in[7];
    const float* nn_w2  = (const float*)d_in[8];
    const float* nn_b2  = (const float*)d_in[9];
    const float* root2  = (const float*)d_in[10];
    const float* bias2  = (const float*)d_in[11];
    const float* nn_w3  = (const float*)d_in[12];
    const float* nn_b3  = (const float*)d_in[13];
    const float* root3  = (const float*)d_in[14];
    const float* bias3  = (const float*)d_in[15];
    const float* lin1_w = (const float*)d_in[16];
    const float* lin1_b = (const float*)d_in[17];
    const float* lin2_w = (const float*)d_in[18];
    const float* lin2_b = (const float*)d_in[19];
    float* out = (float*)d_out;

    // workspace layout
    char* ws = (char*)d_ws;
    size_t off = 0;
    auto alloc = [&](size_t bytes) -> void* {
        void* p = ws + off;
        off += (bytes + 255) & ~(size_t)255;
        return p;
    };
    int*   indptr = (int*)  alloc((N_ + 1) * sizeof(int));
    int*   cursor = (int*)  alloc(N_ * sizeof(int));
    int*   counts = (int*)  alloc(N_ * sizeof(int));
    int*   esrc   = (int*)  alloc(E_ * sizeof(int));
    float* eav    = (float*)alloc(E_ * sizeof(float));
    float* U      = (float*)alloc((size_t)N_ * H * sizeof(float));
    float* V      = (float*)alloc((size_t)N_ * H * sizeof(float));
    float* R      = (float*)alloc((size_t)N_ * H * sizeof(float));
    float* h1     = (float*)alloc((size_t)N_ * H * sizeof(float));
    float* h2     = (float*)alloc((size_t)N_ * H * sizeof(float));
    // pooling buffers contiguous for a single memset: add_p[G*H], cnt[G], max_p[G*H]
    float* add_p  = (float*)alloc((G * H + G + G * H) * sizeof(float));
    float* cnt    = add_p + G * H;
    unsigned int* max_p = (unsigned int*)(cnt + G);

    // ---- CSR build ----
    hipMemsetAsync(counts, 0, N_ * sizeof(int), stream);
    hist_kernel <<<(E_ + 255) / 256, 256, 0, stream>>>(ei, counts);
    scan_kernel <<<1, 1024, 0, stream>>>(counts, indptr, cursor);
    place_kernel<<<(E_ + 255) / 256, 256, 0, stream>>>(ei, ea, cursor, esrc, eav);

    const int pc_grid = (N_ * H + 255) / 256;
    const int ag_grid = (N_ + 7) / 8;     // 8 nodes/block @ 256 threads

    // ---- layer 1 ----
    precompute_kernel<<<pc_grid, 256, 0, stream>>>(x,  F1, nn_w1, nn_b1, root1, bias1, U, V, R);
    conv_agg_kernel  <<<ag_grid, 256, 0, stream>>>(indptr, esrc, eav, U, V, R, h1);
    // ---- layer 2 ----
    precompute_kernel<<<pc_grid, 256, 0, stream>>>(h1, H,  nn_w2, nn_b2, root2, bias2, U, V, R);
    conv_agg_kernel  <<<ag_grid, 256, 0, stream>>>(indptr, esrc, eav, U, V, R, h2);
    // ---- layer 3 ----
    precompute_kernel<<<pc_grid, 256, 0, stream>>>(h2, H,  nn_w3, nn_b3, root3, bias3, U, V, R);
    conv_agg_kernel  <<<ag_grid, 256, 0, stream>>>(indptr, esrc, eav, U, V, R, h1);

    // ---- pooling ----
    hipMemsetAsync(add_p, 0, (G * H + G + G * H) * sizeof(float), stream);
    const int pool_threads = (N_ / 8) * H;   // 40000
    pool_kernel<<<(pool_threads + 255) / 256, 256, 0, stream>>>(h1, batch, add_p, cnt, max_p);

    // ---- readout ----
    readout_kernel<<<G, 64, 0, stream>>>(add_p, cnt, max_p, lin1_w, lin1_b, lin2_w, lin2_b, out);
}

// Round 2
// 219.810 us; speedup vs baseline: 1.2496x; 1.2496x over previous
//
#include <hip/hip_runtime.h>

// Problem constants (fixed by reference)
constexpr int N_  = 10000;   // nodes
constexpr int E_  = 320000;  // edges
constexpr int F1  = 33;      // input features
constexpr int H   = 32;      // hidden
constexpr int G   = 64;      // graphs

constexpr int EBLK = E_ / 256;   // 1250 edge-parallel blocks (exact)
constexpr int NBLK = N_ / 8;     // 1250 node blocks, 8 nodes x 32 lanes (exact)

// ---------------- fused: dst histogram (edge blocks) + layer-1 precompute (node blocks) ---

__global__ __launch_bounds__(256) void k_hist_pre1(
        const int* __restrict__ ei, const float* __restrict__ x,
        const float* __restrict__ A, const float* __restrict__ Bm,
        const float* __restrict__ Rw, const float* __restrict__ bias,
        int* __restrict__ counts, float2* __restrict__ UV, float* __restrict__ R) {
    if (blockIdx.x < EBLK) {
        int e = blockIdx.x * 256 + threadIdx.x;
        atomicAdd(&counts[ei[E_ + e]], 1);
    } else {
        int node = (blockIdx.x - EBLK) * 8 + (threadIdx.x >> 5);
        int f = threadIdx.x & 31;
        float u = 0.f, v = 0.f, r = bias[f];
        const float* xr = x + (size_t)node * F1;
        #pragma unroll
        for (int k = 0; k < F1; ++k) {
            float xv = xr[k];
            u = fmaf(xv, A[k * H + f], u);
            v = fmaf(xv, Bm[k * H + f], v);
            r = fmaf(xv, Rw[k * H + f], r);
        }
        UV[node * H + f] = make_float2(u, v);
        R[node * H + f] = r;
    }
}

// ---------------- single-block exclusive scan -> indptr, cursor ----------------

__global__ void k_scan(const int* __restrict__ counts,
                       int* __restrict__ indptr, int* __restrict__ cursor) {
    const int T = 1024, C = 10;  // T*C = 10240 >= N_
    __shared__ int part[T];
    int t = threadIdx.x;
    int local[C];
    int s = 0;
    #pragma unroll
    for (int j = 0; j < C; ++j) {
        int i = t * C + j;
        int v = (i < N_) ? counts[i] : 0;
        local[j] = s;
        s += v;
    }
    part[t] = s;
    __syncthreads();
    for (int off = 1; off < T; off <<= 1) {
        int xx = (t >= off) ? part[t - off] : 0;
        __syncthreads();
        part[t] += xx;
        __syncthreads();
    }
    int excl = part[t] - s;
    #pragma unroll
    for (int j = 0; j < C; ++j) {
        int i = t * C + j;
        if (i < N_) {
            int val = excl + local[j];
            indptr[i] = val;
            cursor[i] = val;
        }
    }
    if (t == T - 1) indptr[N_] = part[t];
}

// ---------------- placement: CSR edge meta (src, a) packed as int2 ----------------

__global__ __launch_bounds__(256) void k_place(
        const int* __restrict__ ei, const float* __restrict__ ea,
        int* __restrict__ cursor, int2* __restrict__ meta) {
    int e = blockIdx.x * 256 + threadIdx.x;
    int s = ei[e];
    int d = ei[E_ + e];
    int pos = atomicAdd(&cursor[d], 1);
    meta[pos] = make_int2(s, __float_as_int(ea[e]));
}

// ---------------- fused conv-agg (+ next-layer precompute OR pooling) ----------------
// h[i,f] = relu(R[i,f] + sum_e a_e*U[src,f] + V[src,f]); h kept in-register only.

template<bool DO_PRE>
__global__ __launch_bounds__(256) void k_agg(
        const int* __restrict__ indptr, const int2* __restrict__ meta,
        const float2* __restrict__ UV, const float* __restrict__ R,
        const float* __restrict__ A2, const float* __restrict__ B2,
        const float* __restrict__ Rw2, const float* __restrict__ bias2,
        float2* __restrict__ UVo, float* __restrict__ Ro,
        const int* __restrict__ batch, float* __restrict__ add_p,
        float* __restrict__ cnt, unsigned int* __restrict__ max_p) {
    int grp = threadIdx.x >> 5;
    int f = threadIdx.x & 31;
    int node = blockIdx.x * 8 + grp;

    float acc = R[node * H + f];
    int s = indptr[node];
    int e = indptr[node + 1];
    int j = s;
    if (j < e && (j & 1)) {            // peel to 16B-align pair loads
        int2 m = meta[j];
        float2 uv = UV[m.x * H + f];
        acc += __int_as_float(m.y) * uv.x + uv.y;
        ++j;
    }
    for (; j + 1 < e; j += 2) {
        int4 m = *reinterpret_cast<const int4*>(meta + j);   // 2 edges, 16B broadcast
        float2 uv0 = UV[m.x * H + f];
        float2 uv1 = UV[m.z * H + f];
        acc += __int_as_float(m.y) * uv0.x + uv0.y;
        acc += __int_as_float(m.w) * uv1.x + uv1.y;
    }
    if (j < e) {
        int2 m = meta[j];
        float2 uv = UV[m.x * H + f];
        acc += __int_as_float(m.y) * uv.x + uv.y;
    }
    float h = fmaxf(acc, 0.f);         // relu

    if (DO_PRE) {
        // next-layer precompute from in-register h row (cross-lane via shfl, width 32)
        float u = 0.f, v = 0.f, r = bias2[f];
        #pragma unroll
        for (int k = 0; k < H; ++k) {
            float hk = __shfl(h, k, 32);
            u = fmaf(hk, A2[k * H + f], u);
            v = fmaf(hk, B2[k * H + f], v);
            r = fmaf(hk, Rw2[k * H + f], r);
        }
        UVo[node * H + f] = make_float2(u, v);
        Ro[node * H + f] = r;
    } else {
        // fused pooling: block-level run-length reduction over the 8 nodes
        __shared__ float sh[8][33];
        __shared__ int sb[8];
        sh[grp][f] = h;
        if (f == 0) sb[grp] = batch[node];
        __syncthreads();
        if (threadIdx.x < 32) {
            int t = threadIdx.x;
            int cur = sb[0];
            float ssum = 0.f, mx = 0.f, c = 0.f;
            #pragma unroll
            for (int g2 = 0; g2 < 8; ++g2) {
                int b = sb[g2];
                if (b != cur) {
                    atomicAdd(&add_p[cur * H + t], ssum);
                    atomicMax(&max_p[cur * H + t], __float_as_uint(mx));
                    if (t == 0) atomicAdd(&cnt[cur], c);
                    cur = b; ssum = 0.f; mx = 0.f; c = 0.f;
                }
                float v = sh[g2][t];
                ssum += v; mx = fmaxf(mx, v); c += 1.f;
            }
            atomicAdd(&add_p[cur * H + t], ssum);
            atomicMax(&max_p[cur * H + t], __float_as_uint(mx));
            if (t == 0) atomicAdd(&cnt[cur], c);
        }
    }
}

// ---------------- Readout MLP + log_softmax ----------------

__global__ void k_readout(const float* __restrict__ add_p, const float* __restrict__ cnt,
                          const unsigned int* __restrict__ max_p,
                          const float* __restrict__ w1, const float* __restrict__ b1,
                          const float* __restrict__ w2, const float* __restrict__ b2,
                          float* __restrict__ out) {
    int g = blockIdx.x;      // G blocks
    int f = threadIdx.x;     // 64 threads (use first 32)
    __shared__ float gv[3 * H];
    __shared__ float hid[H];
    if (f < H) {
        float a = add_p[g * H + f];
        float c = fmaxf(cnt[g], 1.0f);
        gv[f]         = a;
        gv[H + f]     = a / c;
        gv[2 * H + f] = __uint_as_float(max_p[g * H + f]);
    }
    __syncthreads();
    if (f < H) {
        float acc = b1[f];
        #pragma unroll 4
        for (int k = 0; k < 3 * H; ++k) acc = fmaf(gv[k], w1[k * H + f], acc);
        hid[f] = (acc > 0.f) ? acc : 0.f;
    }
    __syncthreads();
    if (f == 0) {
        float l0 = b2[0], l1 = b2[1];
        for (int k = 0; k < H; ++k) {
            l0 = fmaf(hid[k], w2[k * 2 + 0], l0);
            l1 = fmaf(hid[k], w2[k * 2 + 1], l1);
        }
        float m = fmaxf(l0, l1);
        float lse = m + logf(expf(l0 - m) + expf(l1 - m));
        out[g * 2 + 0] = l0 - lse;
        out[g * 2 + 1] = l1 - lse;
    }
}

// ---------------- launch ----------------

extern "C" void kernel_launch(void* const* d_in, const int* in_sizes, int n_in,
                              void* d_out, int out_size, void* d_ws, size_t ws_size,
                              hipStream_t stream) {
    const float* x      = (const float*)d_in[0];
    const int*   ei     = (const int*)  d_in[1];
    const float* ea     = (const float*)d_in[2];
    const int*   batch  = (const int*)  d_in[3];
    const float* nn_w1  = (const float*)d_in[4];
    const float* nn_b1  = (const float*)d_in[5];
    const float* root1  = (const float*)d_in[6];
    const float* bias1  = (const float*)d_in[7];
    const float* nn_w2  = (const float*)d_in[8];
    const float* nn_b2  = (const float*)d_in[9];
    const float* root2  = (const float*)d_in[10];
    const float* bias2  = (const float*)d_in[11];
    const float* nn_w3  = (const float*)d_in[12];
    const float* nn_b3  = (const float*)d_in[13];
    const float* root3  = (const float*)d_in[14];
    const float* bias3  = (const float*)d_in[15];
    const float* lin1_w = (const float*)d_in[16];
    const float* lin1_b = (const float*)d_in[17];
    const float* lin2_w = (const float*)d_in[18];
    const float* lin2_b = (const float*)d_in[19];
    float* out = (float*)d_out;

    char* ws = (char*)d_ws;
    size_t off = 0;
    auto alloc = [&](size_t bytes) -> void* {
        void* p = ws + off;
        off += (bytes + 255) & ~(size_t)255;
        return p;
    };
    int*   indptr = (int*)alloc((N_ + 1) * sizeof(int));
    int*   cursor = (int*)alloc(N_ * sizeof(int));
    // one contiguous zero-init chunk: counts | add_p | cnt | max_p
    const size_t zbytes = N_ * sizeof(int) + (G * H + G + G * H) * sizeof(float);
    char*  zchunk = (char*)alloc(zbytes);
    int*   counts = (int*)zchunk;
    float* add_p  = (float*)(zchunk + N_ * sizeof(int));
    float* cnt    = add_p + G * H;
    unsigned int* max_p = (unsigned int*)(cnt + G);
    int2*   meta = (int2*)  alloc((size_t)E_ * sizeof(int2));
    float2* UV1  = (float2*)alloc((size_t)N_ * H * sizeof(float2));
    float2* UV2  = (float2*)alloc((size_t)N_ * H * sizeof(float2));
    float2* UV3  = (float2*)alloc((size_t)N_ * H * sizeof(float2));
    float*  R1   = (float*) alloc((size_t)N_ * H * sizeof(float));
    float*  R2   = (float*) alloc((size_t)N_ * H * sizeof(float));
    float*  R3   = (float*) alloc((size_t)N_ * H * sizeof(float));

    hipMemsetAsync(zchunk, 0, zbytes, stream);

    // CSR build + layer-1 precompute (fused, independent halves of the grid)
    k_hist_pre1<<<EBLK + NBLK, 256, 0, stream>>>(ei, x, nn_w1, nn_b1, root1, bias1,
                                                 counts, UV1, R1);
    k_scan <<<1, 1024, 0, stream>>>(counts, indptr, cursor);
    k_place<<<EBLK, 256, 0, stream>>>(ei, ea, cursor, meta);

    // layer 1 agg + layer 2 precompute
    k_agg<true><<<NBLK, 256, 0, stream>>>(indptr, meta, UV1, R1,
                                          nn_w2, nn_b2, root2, bias2, UV2, R2,
                                          nullptr, nullptr, nullptr, nullptr);
    // layer 2 agg + layer 3 precompute
    k_agg<true><<<NBLK, 256, 0, stream>>>(indptr, meta, UV2, R2,
                                          nn_w3, nn_b3, root3, bias3, UV3, R3,
                                          nullptr, nullptr, nullptr, nullptr);
    // layer 3 agg + fused pooling
    k_agg<false><<<NBLK, 256, 0, stream>>>(indptr, meta, UV3, R3,
                                           nullptr, nullptr, nullptr, nullptr, nullptr, nullptr,
                                           batch, add_p, cnt, max_p);

    k_readout<<<G, 64, 0, stream>>>(add_p, cnt, max_p, lin1_w, lin1_b, lin2_w, lin2_b, out);
}